// Round 2
// baseline (513.151 us; speedup 1.0000x reference)
//
#include <hip/hip_runtime.h>
#include <cstddef>

// EdgeAttention: fused Sobel-edge -> depthwise3x3 -> BN(eval) -> ReLU
// B=16, C=256, H=128, W=128, fp32. Memory-bound; single fused kernel.

#define BB 16
#define CC 256
#define HH 128
#define WW 128
#define TY 16          // output rows per block
#define XROWS (TY + 4) // 20: input rows incl. halo 2
#define XCOLS (WW + 4) // 132: input cols incl. halo 2
#define EROWS (TY + 2) // 18: edge rows incl. halo 1
#define ECOLS (WW + 2) // 130: edge cols incl. halo 1
#define XSTR 132
#define ESTR 132
#define EPS 1e-5f

__global__ __launch_bounds__(256) void edge_attn_fused(
    const float* __restrict__ x,
    const float* __restrict__ dw,      // [C,1,3,3]
    const float* __restrict__ gamma,
    const float* __restrict__ beta,
    const float* __restrict__ mean,
    const float* __restrict__ var,
    float* __restrict__ out)
{
    __shared__ float sx[XROWS * XSTR];
    __shared__ float se[EROWS * ESTR];

    const int tid  = threadIdx.x;
    const int tile = blockIdx.x & 7;        // H/TY = 8 tiles per (b,c) image
    const int bc   = blockIdx.x >> 3;       // b*C + c
    const int c    = bc & (CC - 1);
    const int y0   = tile * TY;

    const float* __restrict__ xp = x + (size_t)bc * (HH * WW);

    // ---- stage 1: load x strip with halo 2, zero-padded ----
    for (int idx = tid; idx < XROWS * XCOLS; idx += 256) {
        int r   = idx / XCOLS;
        int col = idx - r * XCOLS;
        int gr  = y0 - 2 + r;
        int gc  = col - 2;
        float v = 0.0f;
        if ((unsigned)gr < (unsigned)HH && (unsigned)gc < (unsigned)WW)
            v = xp[gr * WW + gc];
        sx[r * XSTR + col] = v;
    }
    __syncthreads();

    // ---- stage 2: Sobel edge into LDS (halo 1) ----
    // se[er][ec] = edge at global (row y0-1+er, col ec-1).
    // IMPORTANT: edge map is zero OUTSIDE the image (second conv zero-pads
    // the edge map, not a computed sobel of padded x).
    for (int idx = tid; idx < EROWS * ECOLS; idx += 256) {
        int er = idx / ECOLS;
        int ec = idx - er * ECOLS;
        int ger = y0 - 1 + er;   // global edge row
        int gec = ec - 1;        // global edge col
        float v = 0.0f;
        if ((unsigned)ger < (unsigned)HH && (unsigned)gec < (unsigned)WW) {
            const float* p0 = &sx[er * XSTR + ec];
            const float* p1 = p0 + XSTR;
            const float* p2 = p1 + XSTR;
            float a00 = p0[0], a01 = p0[1], a02 = p0[2];
            float a10 = p1[0],              a12 = p1[2];
            float a20 = p2[0], a21 = p2[1], a22 = p2[2];
            // cross-correlation with sobel kernels (XLA conv does not flip)
            float gx = (a02 - a00) + 2.0f * (a12 - a10) + (a22 - a20);
            float gy = (a20 - a00) + 2.0f * (a21 - a01) + (a22 - a02);
            v = 0.5f * (fabsf(gx) + fabsf(gy));
        }
        se[er * ESTR + ec] = v;
    }
    __syncthreads();

    // ---- stage 3: depthwise 3x3 + BN + ReLU ----
    const float* __restrict__ wp = dw + c * 9;   // broadcast, L1-hit
    const float w0 = wp[0], w1 = wp[1], w2 = wp[2];
    const float w3 = wp[3], w4 = wp[4], w5 = wp[5];
    const float w6 = wp[6], w7 = wp[7], w8 = wp[8];
    const float inv  = gamma[c] / sqrtf(var[c] + EPS);
    const float bias = beta[c] - mean[c] * inv;

    const int ocol = tid & 127;
    const int r0   = tid >> 7;   // 0..1
    float* __restrict__ op = out + (size_t)bc * (HH * WW);

    for (int r = r0; r < TY; r += 2) {
        const float* e0 = &se[r * ESTR + ocol];
        const float* e1 = e0 + ESTR;
        const float* e2 = e1 + ESTR;
        float acc = w0 * e0[0] + w1 * e0[1] + w2 * e0[2]
                  + w3 * e1[0] + w4 * e1[1] + w5 * e1[2]
                  + w6 * e2[0] + w7 * e2[1] + w8 * e2[2];
        float yv = acc * inv + bias;
        op[(y0 + r) * WW + ocol] = fmaxf(yv, 0.0f);
    }
}

extern "C" void kernel_launch(void* const* d_in, const int* in_sizes, int n_in,
                              void* d_out, int out_size, void* d_ws, size_t ws_size,
                              hipStream_t stream) {
    const float* x     = (const float*)d_in[0];
    const float* dw    = (const float*)d_in[1];
    const float* gamma = (const float*)d_in[2];
    const float* beta  = (const float*)d_in[3];
    const float* mean  = (const float*)d_in[4];
    const float* var   = (const float*)d_in[5];
    float* out = (float*)d_out;

    const int nblocks = BB * CC * (HH / TY);   // 16*256*8 = 32768
    edge_attn_fused<<<nblocks, 256, 0, stream>>>(x, dw, gamma, beta, mean, var, out);
}

// Round 3
// 472.254 us; speedup vs baseline: 1.0866x; 1.0866x over previous
//
#include <hip/hip_runtime.h>
#include <cstddef>

// EdgeAttention: fused Sobel-edge -> depthwise3x3 -> BN(eval) -> ReLU
// B=16, C=256, H=128, W=128, fp32.
// R3: fully float4-vectorized; full-width tiles so column halos are
// compile-time zero; no div/mod in loops.

#define BB 16
#define CC 256
#define HH 128
#define WW 128
#define TY 16            // output rows per block
#define XROWS (TY + 4)   // 20 x rows incl. halo 2
#define EROWS (TY + 2)   // 18 edge rows incl. halo 1
#define XSTR 136         // floats per LDS row (544B, 16B-aligned slots)
// layout: image col c -> LDS offset c+4 ; halo slots 2,3 (left) 132,133 (right)
#define EPS 1e-5f

__global__ __launch_bounds__(256) void edge_attn_fused(
    const float* __restrict__ x,
    const float* __restrict__ dw,
    const float* __restrict__ gamma,
    const float* __restrict__ beta,
    const float* __restrict__ mean,
    const float* __restrict__ var,
    float* __restrict__ out)
{
    __shared__ __align__(16) float sx[XROWS * XSTR];
    __shared__ __align__(16) float se[EROWS * XSTR];

    const int tid  = threadIdx.x;
    const int tile = blockIdx.x & 7;      // 8 row-tiles per image
    const int bc   = blockIdx.x >> 3;     // b*C + c
    const int c    = bc & (CC - 1);
    const int y0   = tile * TY;

    const float* __restrict__ xp = x + (size_t)bc * (HH * WW);

    // ---- stage 1: vector-copy 20 rows x 128 cols into LDS (zero pad rows) ----
    for (int i = tid; i < XROWS * 32; i += 256) {
        int r  = i >> 5;
        int c4 = i & 31;
        int gr = y0 - 2 + r;
        float4 v = make_float4(0.f, 0.f, 0.f, 0.f);
        if ((unsigned)gr < (unsigned)HH)
            v = *(const float4*)(xp + gr * WW + (c4 << 2));
        *(float4*)(&sx[r * XSTR + 4 + (c4 << 2)]) = v;
    }
    // zero the 4 always-outside halo cols per x row
    if (tid < XROWS * 4) {
        int r = tid >> 2, k = tid & 3;
        sx[r * XSTR + ((k < 2) ? (2 + k) : (130 + k))] = 0.f;
    }
    // zero the 2 always-outside halo cols per edge row
    if (tid >= 128 && tid < 128 + EROWS * 2) {
        int t = tid - 128;
        se[(t >> 1) * XSTR + ((t & 1) ? 132 : 3)] = 0.f;
    }
    __syncthreads();

    // ---- stage 2: Sobel -> edge LDS (rows outside image are zero) ----
    for (int i = tid; i < EROWS * 32; i += 256) {
        int r   = i >> 5;
        int c4  = i & 31;
        int ger = y0 - 1 + r;
        float4 ev = make_float4(0.f, 0.f, 0.f, 0.f);
        if ((unsigned)ger < (unsigned)HH) {
            const float* p0 = &sx[r * XSTR + 4 + (c4 << 2)];
            const float* p1 = p0 + XSTR;
            const float* p2 = p0 + 2 * XSTR;
            float4 m0 = *(const float4*)p0; float lt0 = p0[-1], rt0 = p0[4];
            float4 m1 = *(const float4*)p1; float lt1 = p1[-1], rt1 = p1[4];
            float4 m2 = *(const float4*)p2; float lt2 = p2[-1], rt2 = p2[4];
            // col j: left,center,right per row; cross-correlation Sobel
            #define SOB(a0l,a0c,a0r,a1l,a1r,a2l,a2c,a2r) \
                (0.5f * (fabsf(((a0r)-(a0l)) + 2.f*((a1r)-(a1l)) + ((a2r)-(a2l))) \
                       + fabsf(((a2l)-(a0l)) + 2.f*((a2c)-(a0c)) + ((a2r)-(a0r)))))
            ev.x = SOB(lt0, m0.x, m0.y,  lt1, m1.y,  lt2, m2.x, m2.y);
            ev.y = SOB(m0.x, m0.y, m0.z, m1.x, m1.z, m2.x, m2.y, m2.z);
            ev.z = SOB(m0.y, m0.z, m0.w, m1.y, m1.w, m2.y, m2.z, m2.w);
            ev.w = SOB(m0.z, m0.w, rt0,  m1.z, rt1,  m2.z, m2.w, rt2);
            #undef SOB
        }
        *(float4*)(&se[r * XSTR + 4 + (c4 << 2)]) = ev;
    }
    __syncthreads();

    // ---- stage 3: depthwise 3x3 + BN + ReLU, float4 out ----
    const float* __restrict__ wp = dw + c * 9;
    const float w0 = wp[0], w1 = wp[1], w2 = wp[2];
    const float w3 = wp[3], w4 = wp[4], w5 = wp[5];
    const float w6 = wp[6], w7 = wp[7], w8 = wp[8];
    const float inv  = gamma[c] / sqrtf(var[c] + EPS);
    const float bias = beta[c] - mean[c] * inv;

    float* __restrict__ op = out + (size_t)bc * (HH * WW) + y0 * WW;

    for (int i = tid; i < TY * 32; i += 256) {
        int r  = i >> 5;
        int c4 = i & 31;
        const float* p0 = &se[r * XSTR + 4 + (c4 << 2)];
        const float* p1 = p0 + XSTR;
        const float* p2 = p0 + 2 * XSTR;
        float4 m0 = *(const float4*)p0; float lt0 = p0[-1], rt0 = p0[4];
        float4 m1 = *(const float4*)p1; float lt1 = p1[-1], rt1 = p1[4];
        float4 m2 = *(const float4*)p2; float lt2 = p2[-1], rt2 = p2[4];
        float4 o;
        o.x = w0*lt0  + w1*m0.x + w2*m0.y + w3*lt1  + w4*m1.x + w5*m1.y + w6*lt2  + w7*m2.x + w8*m2.y;
        o.y = w0*m0.x + w1*m0.y + w2*m0.z + w3*m1.x + w4*m1.y + w5*m1.z + w6*m2.x + w7*m2.y + w8*m2.z;
        o.z = w0*m0.y + w1*m0.z + w2*m0.w + w3*m1.y + w4*m1.z + w5*m1.w + w6*m2.y + w7*m2.z + w8*m2.w;
        o.w = w0*m0.z + w1*m0.w + w2*rt0  + w3*m1.z + w4*m1.w + w5*rt1  + w6*m2.z + w7*m2.w + w8*rt2;
        o.x = fmaxf(o.x * inv + bias, 0.f);
        o.y = fmaxf(o.y * inv + bias, 0.f);
        o.z = fmaxf(o.z * inv + bias, 0.f);
        o.w = fmaxf(o.w * inv + bias, 0.f);
        *(float4*)(op + r * WW + (c4 << 2)) = o;
    }
}

extern "C" void kernel_launch(void* const* d_in, const int* in_sizes, int n_in,
                              void* d_out, int out_size, void* d_ws, size_t ws_size,
                              hipStream_t stream) {
    const float* x     = (const float*)d_in[0];
    const float* dw    = (const float*)d_in[1];
    const float* gamma = (const float*)d_in[2];
    const float* beta  = (const float*)d_in[3];
    const float* mean  = (const float*)d_in[4];
    const float* var   = (const float*)d_in[5];
    float* out = (float*)d_out;

    const int nblocks = BB * CC * (HH / TY);   // 32768
    edge_attn_fused<<<nblocks, 256, 0, stream>>>(x, dw, gamma, beta, mean, var, out);
}